// Round 1
// baseline (13703.825 us; speedup 1.0000x reference)
//
#include <hip/hip_runtime.h>
#include <hip/hip_cooperative_groups.h>

namespace cg = cooperative_groups;

// Shapes: B=16, T_ENC=256, T_DEC=64, N_MEL=80, ENC=512, ARNN=1024, DRNN=1024,
// PRENET=256, ATTN_DIM=128, LOC_F=32, LOC_K=31
// Attn LSTM: K = 256(pre) + 512(ctx) + 1024(ah) = 1792, 4096 gate rows
// Dec  LSTM: K = 1024(ah) + 512(ctx) + 1024(dh) = 2560, 4096 gate rows

// ---------------- workspace layout (float offsets) ----------------
static constexpr size_t OFF_WTA  = 0;                            // 1792*4096 blocked-transposed attn W
static constexpr size_t OFF_WTD  = OFF_WTA + (size_t)1792*4096;  // 2560*4096 blocked-transposed dec W
static constexpr size_t OFF_PRET = OFF_WTD + (size_t)2560*4096;  // 64*256*16  prenet out [t][k][b]
static constexpr size_t OFF_PM   = OFF_PRET + (size_t)64*256*16; // 16*256*128 processed memory
static constexpr size_t OFF_MWT  = OFF_PM + (size_t)16*256*128;  // 512*128 mem_W transposed
static constexpr size_t OFF_BA   = OFF_MWT + 512*128;            // 4096 combined attn bias
static constexpr size_t OFF_BD   = OFF_BA + 4096;                // 4096 combined dec bias
static constexpr size_t OFF_CONVT= OFF_BD + 4096;                // 16*256*32 conv out [b][tt][f]
static constexpr size_t OFF_E    = OFF_CONVT + (size_t)16*256*32;// 16*256 exp(energies)
static constexpr size_t OFF_Q    = OFF_E + 16*256;               // 16*128 query [b][d]
static constexpr size_t OFF_AHN  = OFF_Q + 16*128;               // 16*1024 ah natural [b][u]
static constexpr size_t OFF_ZERO = OFF_AHN + 16*1024;            // ---- zero-init region ----
static constexpr size_t OFF_AHT  = OFF_ZERO;                     // 65*1024*16  ah hist [s][u][b]
static constexpr size_t OFF_CTXT = OFF_AHT + (size_t)65*16384;   // 65*512*16   ctx hist [s][k][b]
static constexpr size_t OFF_DHT  = OFF_CTXT + (size_t)65*8192;   // 65*1024*16  dh hist
static constexpr size_t OFF_ACT  = OFF_DHT + (size_t)65*16384;   // 1024*16 attn c state
static constexpr size_t OFF_DCT  = OFF_ACT + 16384;              // 1024*16 dec c state
static constexpr size_t OFF_AW   = OFF_DCT + 16384;              // 16*256 attn weights
static constexpr size_t OFF_AWC  = OFF_AW + 4096;                // 16*256 cumulative
static constexpr size_t OFF_END  = OFF_AWC + 4096;               // total ~21.54M floats (~86 MB)

struct KParams {
  const float* memory;   // (16,256,512)
  const int*   mlen;     // (16)
  const float* qW;       // (128,1024)
  const float* convW;    // (32,2,31)
  const float* ldW;      // (128,32)
  const float* attnv;    // (128)
  const float* projW;    // (80,1536)
  const float* projb;    // (80)
  const float* gateW;    // (1536)
  const float* gateb;    // (1)
  float* ws;
  float* out;
};

__device__ __forceinline__ float sigmf(float x) { return 1.f / (1.f + expf(-x)); }

// ---------------- prep: blocked transpose of LSTM weights ----------------
// WT[k*4096 + bk*16 + g*4 + ul] = Wrow(j = g*1024 + bk*4 + ul)[k]
// so block bk's 16 gate rows are contiguous per k (one 64B line per float4 group).
__global__ void k_transpose(const float* __restrict__ Wih, const float* __restrict__ Whh,
                            float* __restrict__ WT, int Kih) {
  int kt = blockIdx.x, jt = blockIdx.y, th = threadIdx.x;
  int k0 = kt * 64, jp0 = jt * 64;
  __shared__ float tile[64][65];
  int kk = th & 63, r0 = th >> 6;
  for (int i = 0; i < 16; ++i) {
    int r = r0 + i * 4;
    int jp = jp0 + r;
    int bkq = jp >> 4, rr = jp & 15;
    int g = rr >> 2, ul = rr & 3;
    int j = g * 1024 + bkq * 4 + ul;
    int k = k0 + kk;
    tile[r][kk] = (k < Kih) ? Wih[(size_t)j * Kih + k] : Whh[(size_t)j * 1024 + (k - Kih)];
  }
  __syncthreads();
  for (int i = 0; i < 16; ++i) {
    int kk2 = r0 + i * 4;
    WT[((size_t)(k0 + kk2)) * 4096 + jp0 + (th & 63)] = tile[th & 63][kk2];
  }
}

// ---------------- prep: mem_W transpose + combined biases ----------------
__global__ void k_smallprep(const float* __restrict__ memW,
                            const float* __restrict__ abih, const float* __restrict__ abhh,
                            const float* __restrict__ dbih, const float* __restrict__ dbhh,
                            float* __restrict__ ws) {
  int idx = blockIdx.x * 256 + threadIdx.x;
  if (idx < 65536) {
    int k = idx >> 7, d = idx & 127;
    ws[OFF_MWT + idx] = memW[d * 512 + k];
  } else if (idx < 65536 + 4096) {
    int j = idx - 65536;
    ws[OFF_BA + j] = abih[j] + abhh[j];
  } else if (idx < 65536 + 8192) {
    int j = idx - 65536 - 4096;
    ws[OFF_BD + j] = dbih[j] + dbhh[j];
  }
}

// ---------------- prep: prenet (both layers), output transposed [t][k][b] ----------------
__global__ void k_prenet(const float* __restrict__ dec_in,
                         const float* __restrict__ W1, const float* __restrict__ b1,
                         const float* __restrict__ W2, const float* __restrict__ b2,
                         float* __restrict__ ws) {
  int s = blockIdx.x, b = blockIdx.y, th = threadIdx.x;
  __shared__ float frame[80];
  __shared__ float h1[256];
  if (th < 80) frame[th] = (s == 0) ? 0.f : dec_in[(b * 80 + th) * 64 + (s - 1)];
  __syncthreads();
  float a = b1[th];
  const float* w1r = W1 + th * 80;
  for (int m = 0; m < 80; ++m) a += w1r[m] * frame[m];
  h1[th] = fmaxf(a, 0.f);
  __syncthreads();
  float a2 = b2[th];
  const float* w2r = W2 + th * 256;
  for (int i = 0; i < 256; ++i) a2 += w2r[i] * h1[i];
  ws[OFF_PRET + s * 4096 + th * 16 + b] = fmaxf(a2, 0.f);
}

// ---------------- prep: processed_memory = memory @ mem_W^T ----------------
__global__ void k_pm(const float* __restrict__ memory, float* __restrict__ ws) {
  int bk = blockIdx.x, th = threadIdx.x;
  int b = bk >> 4, t0 = (bk & 15) * 16;
  __shared__ float mrow[16 * 512];
  for (int i = 0; i < 8; ++i) {
    int fi4 = i * 256 + th;
    int tl = fi4 >> 7, k4 = (fi4 & 127) << 2;
    *(float4*)&mrow[tl * 512 + k4] =
        *(const float4*)&memory[((size_t)(b * 256 + t0 + tl)) * 512 + k4];
  }
  __syncthreads();
  int d = th & 127, tl0 = th >> 7;
  float acc[8] = {};
  const float* mWT = ws + OFF_MWT;
  for (int k = 0; k < 512; ++k) {
    float w = mWT[k * 128 + d];
#pragma unroll
    for (int i = 0; i < 8; ++i) acc[i] += w * mrow[(tl0 + i * 2) * 512 + k];
  }
  for (int i = 0; i < 8; ++i)
    ws[OFF_PM + ((size_t)(b * 256 + t0 + tl0 + i * 2)) * 128 + d] = acc[i];
}

// ---------------- main persistent cooperative kernel ----------------
__global__ void __launch_bounds__(256, 1) k_main(KParams p) {
  cg::grid_group grid = cg::this_grid();
  const int th = threadIdx.x;
  const int bk = blockIdx.x;
  float* ws = p.ws;
  __shared__ float sm[14592];  // 58.4 KB

  const int tile = th & 15, kc = th >> 4;
  const int g = tile >> 2, bq = tile & 3;

  // ================= loop 1: attention recurrence =================
  for (int t = 0; t < 64; ++t) {
    // ---- Phase A: location conv + attn-LSTM gates + state update ----
    {
      // location conv: 131072 outputs, 2 per thread; convT[b][tt][f]
      {
        int o0 = bk * 512 + th * 2;
        int b = o0 >> 13, tt = (o0 >> 5) & 255, f = o0 & 31;
        float acc0 = 0.f, acc1 = 0.f;
        const float* w0 = p.convW + f * 62;
        const float* w1v = p.convW + (f + 1) * 62;
        for (int i = 0; i < 2; ++i) {
          const float* src = ws + (i ? OFF_AWC : OFF_AW) + b * 256;
#pragma unroll
          for (int kk = 0; kk < 31; ++kk) {
            int pos = tt + kk - 15;
            float v = (pos >= 0 && pos < 256) ? src[pos] : 0.f;
            acc0 += v * w0[i * 31 + kk];
            acc1 += v * w1v[i * 31 + kk];
          }
        }
        ws[OFF_CONVT + o0] = acc0;
        ws[OFF_CONVT + o0 + 1] = acc1;
      }
      // gates: block owns hidden units u = bk*4..bk*4+3, 16 rows (4 gates x 4 u)
      float acc[4][4] = {};
      for (int s = 0; s < 4; ++s) {          // 4 K-stages of 448
        __syncthreads();
#pragma unroll
        for (int i = 0; i < 7; ++i) {        // stage x[k][b] (448x16) into LDS
          int fi4 = i * 256 + th;
          int k = s * 448 + (fi4 >> 2);
          int b4 = (fi4 & 3) << 2;
          const float* src;
          if (k < 256)      src = ws + OFF_PRET + t * 4096 + k * 16 + b4;
          else if (k < 768) src = ws + OFF_CTXT + (size_t)t * 8192 + (k - 256) * 16 + b4;
          else              src = ws + OFF_AHT + (size_t)t * 16384 + (k - 768) * 16 + b4;
          *(float4*)&sm[fi4 << 2] = *(const float4*)src;
        }
        __syncthreads();
        const float* wbase = ws + OFF_WTA + (size_t)(s * 448 + kc * 28) * 4096 + bk * 16 + g * 4;
        const float* xbase = sm + (kc * 28) * 16 + bq * 4;
#pragma unroll 4
        for (int i = 0; i < 28; ++i) {
          float4 xv = *(const float4*)(xbase + i * 16);
          float4 wv = *(const float4*)(wbase + (size_t)i * 4096);
          acc[0][0] += wv.x * xv.x; acc[0][1] += wv.x * xv.y; acc[0][2] += wv.x * xv.z; acc[0][3] += wv.x * xv.w;
          acc[1][0] += wv.y * xv.x; acc[1][1] += wv.y * xv.y; acc[1][2] += wv.y * xv.z; acc[1][3] += wv.y * xv.w;
          acc[2][0] += wv.z * xv.x; acc[2][1] += wv.z * xv.y; acc[2][2] += wv.z * xv.z; acc[2][3] += wv.z * xv.w;
          acc[3][0] += wv.w * xv.x; acc[3][1] += wv.w * xv.y; acc[3][2] += wv.w * xv.z; acc[3][3] += wv.w * xv.w;
        }
      }
      __syncthreads();
#pragma unroll
      for (int ul = 0; ul < 4; ++ul)
#pragma unroll
        for (int bl = 0; bl < 4; ++bl)
          sm[kc * 256 + (g * 4 + ul) * 16 + bq * 4 + bl] = acc[ul][bl];
      __syncthreads();
      {  // K-chunk reduce + bias -> gbuf at sm[4096..4352)
        int row = th >> 4, b = th & 15;
        float ssum = 0.f;
#pragma unroll
        for (int k2 = 0; k2 < 16; ++k2) ssum += sm[k2 * 256 + row * 16 + b];
        ssum += ws[OFF_BA + (row >> 2) * 1024 + bk * 4 + (row & 3)];
        sm[4096 + row * 16 + b] = ssum;
      }
      __syncthreads();
      if (th < 64) {  // LSTM pointwise update for 4 u x 16 b
        int ul = th >> 4, b = th & 15;
        int u = bk * 4 + ul;
        float gi = sm[4096 + ul * 16 + b];
        float gf = sm[4096 + (4 + ul) * 16 + b];
        float gc = sm[4096 + (8 + ul) * 16 + b];
        float go = sm[4096 + (12 + ul) * 16 + b];
        float c = ws[OFF_ACT + u * 16 + b];
        float c2 = sigmf(gf) * c + sigmf(gi) * tanhf(gc);
        float h2 = sigmf(go) * tanhf(c2);
        ws[OFF_ACT + u * 16 + b] = c2;
        ws[OFF_AHT + (size_t)(t + 1) * 16384 + u * 16 + b] = h2;
        ws[OFF_AHN + b * 1024 + u] = h2;
      }
    }
    grid.sync();

    // ---- Phase B: query = ah @ query_W^T ----
    {
      int d = bk >> 1, b = ((bk & 1) << 3) + (th >> 5);
      int lane = th & 31;
      const float* qrow = p.qW + d * 1024;
      const float* ah = ws + OFF_AHN + b * 1024;
      float acc = 0.f;
      for (int k = lane; k < 1024; k += 32) acc += qrow[k] * ah[k];
#pragma unroll
      for (int off = 16; off; off >>= 1) acc += __shfl_xor(acc, off);
      if (lane == 0) ws[OFF_Q + b * 128 + d] = acc;
    }
    grid.sync();

    // ---- Phase C: energies -> exp (max-free softmax numerator) ----
    {
      int b = bk >> 4, t0 = (bk & 15) << 4;
      float* cbuf = sm;         // 512: conv vals for 16 tt
      float* qbuf = sm + 512;   // 128
      float* vbuf = sm + 640;   // 128
      {
        int i2 = th << 1;
        const float* src = ws + OFF_CONVT + b * 8192 + t0 * 32;
        cbuf[i2] = src[i2];
        cbuf[i2 + 1] = src[i2 + 1];
        if (th < 128) qbuf[th] = ws[OFF_Q + b * 128 + th];
        else vbuf[th - 128] = p.attnv[th - 128];
      }
      __syncthreads();
      int w = th >> 6, lane = th & 63;
      int len = p.mlen[b];
      for (int tl = 0; tl < 4; ++tl) {
        int tt = t0 + (w << 2) + tl;
        float e = 0.f;
#pragma unroll
        for (int dd = 0; dd < 2; ++dd) {
          int d = lane + (dd << 6);
          float sum = qbuf[d] + ws[OFF_PM + ((size_t)(b * 256 + tt)) * 128 + d];
          const float* lw = p.ldW + d * 32;
          const float* cv = cbuf + ((tt - t0) << 5);
#pragma unroll 8
          for (int f = 0; f < 32; ++f) sum += cv[f] * lw[f];
          e += vbuf[d] * tanhf(sum);
        }
#pragma unroll
        for (int off = 32; off; off >>= 1) e += __shfl_xor(e, off);
        if (lane == 0) ws[OFF_E + b * 256 + tt] = (tt < len) ? expf(e) : 0.f;
      }
    }
    grid.sync();

    // ---- Phase D: softmax denom + context + alignment outputs ----
    {
      int b = bk >> 4, d0 = (bk & 15) << 5;
      float* ebuf = sm;          // 256
      float* dpart = sm + 256;   // 256
      float* wr = sm + 512;      // 4
      ebuf[th] = ws[OFF_E + b * 256 + th];
      __syncthreads();
      float v0 = ebuf[th];
#pragma unroll
      for (int off = 32; off; off >>= 1) v0 += __shfl_xor(v0, off);
      if ((th & 63) == 0) wr[th >> 6] = v0;
      __syncthreads();
      float rden = 1.f / (wr[0] + wr[1] + wr[2] + wr[3]);
      int dd = th & 31, tc = th >> 5;
      const float* mb = p.memory + ((size_t)b * 256) * 512 + d0 + dd;
      float acc = 0.f;
#pragma unroll 4
      for (int i = 0; i < 32; ++i) {
        int tt = (tc << 5) + i;
        acc += ebuf[tt] * mb[(size_t)tt * 512];
      }
      dpart[th] = acc;
      __syncthreads();
      if (th < 32) {
        float ssum = 0.f;
#pragma unroll
        for (int t2 = 0; t2 < 8; ++t2) ssum += dpart[(t2 << 5) + th];
        ws[OFF_CTXT + (size_t)(t + 1) * 8192 + (d0 + th) * 16 + b] = ssum * rden;
      }
      if ((bk & 15) == 0) {
        float a = ebuf[th] * rden;
        ws[OFF_AW + b * 256 + th] = a;
        ws[OFF_AWC + b * 256 + th] += a;
        p.out[82944 + ((size_t)(b * 64 + t)) * 256 + th] = a;
      }
    }
    grid.sync();
  }

  // ================= loop 2: decoder-LSTM recurrence (1 sync/step) =================
  for (int t = 0; t < 64; ++t) {
    float acc[4][4] = {};
    for (int s = 0; s < 4; ++s) {  // 4 K-stages of 640
      __syncthreads();
#pragma unroll
      for (int i = 0; i < 10; ++i) {
        int fi4 = i * 256 + th;
        int k = s * 640 + (fi4 >> 2);
        int b4 = (fi4 & 3) << 2;
        const float* src;
        if (k < 1024)      src = ws + OFF_AHT + (size_t)(t + 1) * 16384 + k * 16 + b4;
        else if (k < 1536) src = ws + OFF_CTXT + (size_t)(t + 1) * 8192 + (k - 1024) * 16 + b4;
        else               src = ws + OFF_DHT + (size_t)t * 16384 + (k - 1536) * 16 + b4;
        *(float4*)&sm[fi4 << 2] = *(const float4*)src;
      }
      __syncthreads();
      const float* wbase = ws + OFF_WTD + (size_t)(s * 640 + kc * 40) * 4096 + bk * 16 + g * 4;
      const float* xbase = sm + (kc * 40) * 16 + bq * 4;
#pragma unroll 4
      for (int i = 0; i < 40; ++i) {
        float4 xv = *(const float4*)(xbase + i * 16);
        float4 wv = *(const float4*)(wbase + (size_t)i * 4096);
        acc[0][0] += wv.x * xv.x; acc[0][1] += wv.x * xv.y; acc[0][2] += wv.x * xv.z; acc[0][3] += wv.x * xv.w;
        acc[1][0] += wv.y * xv.x; acc[1][1] += wv.y * xv.y; acc[1][2] += wv.y * xv.z; acc[1][3] += wv.y * xv.w;
        acc[2][0] += wv.z * xv.x; acc[2][1] += wv.z * xv.y; acc[2][2] += wv.z * xv.z; acc[2][3] += wv.z * xv.w;
        acc[3][0] += wv.w * xv.x; acc[3][1] += wv.w * xv.y; acc[3][2] += wv.w * xv.z; acc[3][3] += wv.w * xv.w;
      }
    }
    __syncthreads();
#pragma unroll
    for (int ul = 0; ul < 4; ++ul)
#pragma unroll
      for (int bl = 0; bl < 4; ++bl)
        sm[kc * 256 + (g * 4 + ul) * 16 + bq * 4 + bl] = acc[ul][bl];
    __syncthreads();
    {
      int row = th >> 4, b = th & 15;
      float ssum = 0.f;
#pragma unroll
      for (int k2 = 0; k2 < 16; ++k2) ssum += sm[k2 * 256 + row * 16 + b];
      ssum += ws[OFF_BD + (row >> 2) * 1024 + bk * 4 + (row & 3)];
      sm[4096 + row * 16 + b] = ssum;
    }
    __syncthreads();
    if (th < 64) {
      int ul = th >> 4, b = th & 15;
      int u = bk * 4 + ul;
      float gi = sm[4096 + ul * 16 + b];
      float gf = sm[4096 + (4 + ul) * 16 + b];
      float gc = sm[4096 + (8 + ul) * 16 + b];
      float go = sm[4096 + (12 + ul) * 16 + b];
      float c = ws[OFF_DCT + u * 16 + b];
      float c2 = sigmf(gf) * c + sigmf(gi) * tanhf(gc);
      float h2 = sigmf(go) * tanhf(c2);
      ws[OFF_DCT + u * 16 + b] = c2;
      ws[OFF_DHT + (size_t)(t + 1) * 16384 + u * 16 + b] = h2;
    }
    grid.sync();
  }

  // ================= epilogue: mel + gate projections =================
  {
    int t = bk & 63, pa = bk >> 6;
    const float* dh = ws + OFF_DHT + (size_t)(t + 1) * 16384;
    const float* cx = ws + OFF_CTXT + (size_t)(t + 1) * 8192;
    int lim = (pa == 3) ? 336 : 320;
    for (int idx = th; idx < lim; idx += 256) {
      if (idx < 320) {
        int mi = idx >> 4, b = idx & 15, m = pa * 20 + mi;
        const float* wr = p.projW + (size_t)m * 1536;
        float acc = 0.f;
        for (int k = 0; k < 1024; ++k) acc += wr[k] * dh[k * 16 + b];
        for (int k = 0; k < 512; ++k)  acc += wr[1024 + k] * cx[k * 16 + b];
        p.out[((size_t)(b * 80 + m)) * 64 + t] = acc + p.projb[m];
      } else {
        int b = idx - 320;
        float acc = 0.f;
        for (int k = 0; k < 1024; ++k) acc += p.gateW[k] * dh[k * 16 + b];
        for (int k = 0; k < 512; ++k)  acc += p.gateW[1024 + k] * cx[k * 16 + b];
        p.out[81920 + b * 64 + t] = acc + p.gateb[0];
      }
    }
  }
}

// ---------------- host launcher ----------------
extern "C" void kernel_launch(void* const* d_in, const int* in_sizes, int n_in,
                              void* d_out, int out_size, void* d_ws, size_t ws_size,
                              hipStream_t stream) {
  (void)in_sizes; (void)n_in; (void)out_size; (void)ws_size;
  const float* memory = (const float*)d_in[0];
  const float* dec_in = (const float*)d_in[1];
  const int*   mlen   = (const int*)d_in[2];
  const float* pW1    = (const float*)d_in[3];
  const float* pb1    = (const float*)d_in[4];
  const float* pW2    = (const float*)d_in[5];
  const float* pb2    = (const float*)d_in[6];
  const float* aWih   = (const float*)d_in[7];
  const float* aWhh   = (const float*)d_in[8];
  const float* abih   = (const float*)d_in[9];
  const float* abhh   = (const float*)d_in[10];
  const float* qW     = (const float*)d_in[11];
  const float* memW   = (const float*)d_in[12];
  const float* convW  = (const float*)d_in[13];
  const float* ldW    = (const float*)d_in[14];
  const float* attnv  = (const float*)d_in[15];
  const float* dWih   = (const float*)d_in[16];
  const float* dWhh   = (const float*)d_in[17];
  const float* dbih   = (const float*)d_in[18];
  const float* dbhh   = (const float*)d_in[19];
  const float* projW  = (const float*)d_in[20];
  const float* projb  = (const float*)d_in[21];
  const float* gateW  = (const float*)d_in[22];
  const float* gateb  = (const float*)d_in[23];
  float* ws = (float*)d_ws;
  float* out = (float*)d_out;

  // zero recurrent state region (runs every call -> deterministic)
  hipMemsetAsync((char*)d_ws + OFF_ZERO * sizeof(float), 0,
                 (OFF_END - OFF_ZERO) * sizeof(float), stream);

  hipLaunchKernelGGL(k_transpose, dim3(28, 64), dim3(256), 0, stream, aWih, aWhh, ws + OFF_WTA, 768);
  hipLaunchKernelGGL(k_transpose, dim3(40, 64), dim3(256), 0, stream, dWih, dWhh, ws + OFF_WTD, 1536);
  hipLaunchKernelGGL(k_smallprep, dim3(288), dim3(256), 0, stream, memW, abih, abhh, dbih, dbhh, ws);
  hipLaunchKernelGGL(k_prenet, dim3(64, 16), dim3(256), 0, stream, dec_in, pW1, pb1, pW2, pb2, ws);
  hipLaunchKernelGGL(k_pm, dim3(256), dim3(256), 0, stream, memory, ws);

  KParams p{memory, mlen, qW, convW, ldW, attnv, projW, projb, gateW, gateb, ws, out};
  void* args[] = { &p };
  hipLaunchCooperativeKernel((void*)k_main, dim3(256), dim3(256), args, 0, stream);
}

// Round 2
// 9067.983 us; speedup vs baseline: 1.5112x; 1.5112x over previous
//
#include <hip/hip_runtime.h>
#include <hip/hip_cooperative_groups.h>

namespace cg = cooperative_groups;

typedef __attribute__((ext_vector_type(8))) short short8;
typedef __attribute__((ext_vector_type(4))) float f32x4;
typedef unsigned short u16;
typedef unsigned int u32;

// Shapes: B=16, T_ENC=256, T_DEC=64, N_MEL=80, ENC=512, ARNN=DRNN=1024,
// PRENET=256, ATTN_DIM=128, LOC_F=32, LOC_K=31
// attn LSTM K = 256+512+1024 = 1792 (56 tiles of 32); dec K = 1024+512+1024 = 2560 (80 tiles)
// MFMA 16x16x32 bf16 fragments: A tile (16 rows x 32 k), B tile (32 k x 16 b):
//   lane = kgroup*16 + (row|col), kgroup=(k>>3)&3, elem = k&7; tile = 64 lanes x 8 elems = 1KB bf16.
// C/D: col = lane&15, row = (lane>>4)*4 + reg  [HW-verified]

// ---------------- workspace byte offsets ----------------
static constexpr size_t OFF_WFA   = 0;                 // 256*56*1024 = 14,680,064
static constexpr size_t OFF_WFD   = 14680064;          // 256*80*1024 = 20,971,520
static constexpr size_t OFF_PREF  = 35651584;          // 64*8*1024  = 524,288
static constexpr size_t OFF_QWB   = 36175872;          // 128*1024*2 = 262,144
static constexpr size_t OFF_MWT   = 36438016;          // 512*128*4  = 262,144
static constexpr size_t OFF_BA    = 36700160;          // 4096*4
static constexpr size_t OFF_BD    = 36716544;          // 4096*4
static constexpr size_t OFF_PM    = 36732928;          // 16*256*128*4 = 2,097,152
static constexpr size_t OFF_CONVT = 38830080;          // 16*256*32*4 = 1,048,576
static constexpr size_t OFF_E     = 39878656;          // 16*256*4
static constexpr size_t OFF_CTXF  = 39895040;          // 65*512*16*4 = 2,129,920
static constexpr size_t OFF_DHF   = 42024960;          // 65*1024*16*4 = 4,259,840
static constexpr size_t OFF_AHFD  = 46284800;          // 65*32*1024 = 2,129,920
static constexpr size_t OFF_CTXFD = 48414720;          // 65*16*1024 = 1,064,960
// ---- zero-init region ----
static constexpr size_t OFF_XBUFA = 49479680;          // 2*48*1024 = 98,304  (tiles 8..55: ctx 0..15, ah 16..47)
static constexpr size_t OFF_DHB   = 49577984;          // 2*32*1024 = 65,536
static constexpr size_t OFF_ACT   = 49643520;          // 1024*16*4
static constexpr size_t OFF_DCT   = 49709056;          // 1024*16*4
static constexpr size_t OFF_AW    = 49774592;          // 16*256*4
static constexpr size_t OFF_AWC   = 49790976;          // 16*256*4
static constexpr size_t OFF_AHN   = 49807360;          // 16*1024*4
static constexpr size_t OFF_END   = 49872896;
static constexpr size_t ZERO_BYTES = OFF_END - OFF_XBUFA;  // 393,216

__device__ __forceinline__ float sigmf(float x) { return 1.f / (1.f + expf(-x)); }
__device__ __forceinline__ u16 f2bf(float f) {
  u32 u = __float_as_uint(f);
  return (u16)((u + 0x7FFFu + ((u >> 16) & 1u)) >> 16);
}
__device__ __forceinline__ float bf2f(u16 x) { return __uint_as_float(((u32)x) << 16); }

// ---------------- prep: LSTM weights -> bf16 A-fragment layout ----------------
// dst[bk][s][lane][8] bf16; rows jp = bk*16 + g*4 + ul <-> j = g*1024 + bk*4 + ul
__global__ void k_wfrag(const float* __restrict__ Wih, const float* __restrict__ Whh,
                        char* __restrict__ dst, int NT, int Kih) {
  int idx = blockIdx.x * 256 + threadIdx.x;   // (bk*NT + s)*64 + l
  int l = idx & 63;
  int st = idx >> 6;
  int s = st % NT, bk = st / NT;
  int r = l & 15, kg = l >> 4;
  int j = (r >> 2) * 1024 + bk * 4 + (r & 3);
  int k0 = s * 32 + kg * 8;
  const float* src = (k0 < Kih) ? (Wih + (size_t)j * Kih + k0)
                                : (Whh + (size_t)j * 1024 + (k0 - Kih));
  short8 v;
#pragma unroll
  for (int e = 0; e < 8; ++e) v[e] = (short)f2bf(src[e]);
  *(short8*)(dst + (size_t)idx * 16) = v;
}

// ---------------- prep: memW^T, combined biases, qW bf16 ----------------
__global__ void k_smallprep(const float* __restrict__ memW,
                            const float* __restrict__ abih, const float* __restrict__ abhh,
                            const float* __restrict__ dbih, const float* __restrict__ dbhh,
                            const float* __restrict__ qW, char* __restrict__ wsb) {
  int idx = blockIdx.x * 256 + threadIdx.x;
  if (idx < 65536) {
    int k = idx >> 7, d = idx & 127;
    ((float*)(wsb + OFF_MWT))[idx] = memW[d * 512 + k];
  } else if (idx < 69632) {
    int j = idx - 65536;
    ((float*)(wsb + OFF_BA))[j] = abih[j] + abhh[j];
  } else if (idx < 73728) {
    int j = idx - 69632;
    ((float*)(wsb + OFF_BD))[j] = dbih[j] + dbhh[j];
  } else if (idx < 204800) {
    int j = idx - 73728;
    ((u16*)(wsb + OFF_QWB))[j] = f2bf(qW[j]);
  }
}

// ---------------- prep: prenet -> bf16 B-fragment layout per step ----------------
__global__ void k_prenet(const float* __restrict__ dec_in,
                         const float* __restrict__ W1, const float* __restrict__ b1,
                         const float* __restrict__ W2, const float* __restrict__ b2,
                         char* __restrict__ wsb) {
  int s = blockIdx.x, b = blockIdx.y, th = threadIdx.x;
  __shared__ float frame[80];
  __shared__ float h1[256];
  if (th < 80) frame[th] = (s == 0) ? 0.f : dec_in[(b * 80 + th) * 64 + (s - 1)];
  __syncthreads();
  float a = b1[th];
  const float* w1r = W1 + th * 80;
  for (int m = 0; m < 80; ++m) a += w1r[m] * frame[m];
  h1[th] = fmaxf(a, 0.f);
  __syncthreads();
  float a2 = b2[th];
  const float* w2r = W2 + th * 256;
  for (int i = 0; i < 256; ++i) a2 += w2r[i] * h1[i];
  float pre = fmaxf(a2, 0.f);
  int k = th;
  ((u16*)(wsb + OFF_PREF))[(((size_t)s * 8 + (k >> 5)) * 64 + ((k >> 3) & 3) * 16 + b) * 8 + (k & 7)] = f2bf(pre);
}

// ---------------- prep: processed_memory ----------------
__global__ void k_pm(const float* __restrict__ memory, char* __restrict__ wsb) {
  int bk = blockIdx.x, th = threadIdx.x;
  int b = bk >> 4, t0 = (bk & 15) * 16;
  __shared__ float mrow[16 * 512];
  for (int i = 0; i < 8; ++i) {
    int fi4 = i * 256 + th;
    int tl = fi4 >> 7, k4 = (fi4 & 127) << 2;
    *(float4*)&mrow[tl * 512 + k4] =
        *(const float4*)&memory[((size_t)(b * 256 + t0 + tl)) * 512 + k4];
  }
  __syncthreads();
  int d = th & 127, tl0 = th >> 7;
  float acc[8] = {};
  const float* mWT = (const float*)(wsb + OFF_MWT);
  float* pmw = (float*)(wsb + OFF_PM);
  for (int k = 0; k < 512; ++k) {
    float w = mWT[k * 128 + d];
#pragma unroll
    for (int i = 0; i < 8; ++i) acc[i] += w * mrow[(tl0 + i * 2) * 512 + k];
  }
  for (int i = 0; i < 8; ++i)
    pmw[((size_t)(b * 256 + t0 + tl0 + i * 2)) * 128 + d] = acc[i];
}

struct KParams {
  const float* memory;
  const int* mlen;
  const float* convW;
  const float* ldW;
  const float* attnv;
  const float* projW;
  const float* projb;
  const float* gateW;
  const float* gateb;
  char* wsb;
  float* out;
};

// ---------------- main persistent cooperative kernel ----------------
__global__ void __launch_bounds__(512, 2) k_main(KParams p) {
  cg::grid_group grid = cg::this_grid();
  const int th = threadIdx.x;
  const int bk = blockIdx.x;
  char* wsb = p.wsb;
  const int l = th & 63, w = th >> 6;

  __shared__ float smC[2304];
  __shared__ float s2q[128], s2v[128];
  __shared__ float s2ldw[4224];   // [128][33]
  __shared__ float s2conv[1056];  // [32][33]
  __shared__ float s2ah[1024];
  __shared__ float s3e[256], s3part[512], s3wr[4];
  __shared__ float s1cw[1984];    // convW 32*62
  __shared__ float s1aw[64], s1awc[64];

  float* actA = (float*)(wsb + OFF_ACT);
  float* actD = (float*)(wsb + OFF_DCT);
  float* ahn  = (float*)(wsb + OFF_AHN);
  float* awp  = (float*)(wsb + OFF_AW);
  float* awcp = (float*)(wsb + OFF_AWC);
  float* Ebuf = (float*)(wsb + OFF_E);
  float* convT = (float*)(wsb + OFF_CONVT);
  const float* pm = (const float*)(wsb + OFF_PM);
  const float* biasA = (const float*)(wsb + OFF_BA);
  const float* biasD = (const float*)(wsb + OFF_BD);
  const u16* qwb = (const u16*)(wsb + OFF_QWB);

  // persistent LDS staging (step-invariant)
  for (int i = th; i < 1984; i += 512) s1cw[i] = p.convW[i];
  for (int i = th; i < 4096; i += 512) s2ldw[(i >> 5) * 33 + (i & 31)] = p.ldW[i];
  if (th < 128) s2v[th] = p.attnv[th];
  __syncthreads();

  // ================= loop 1: attention recurrence (3 grid syncs/step) =================
  for (int t = 0; t < 64; ++t) {
    const int par = t & 1, par2 = par ^ 1;
    // ---- S1: attn-LSTM gates (MFMA) + location conv ----
    short8 af[7], bfr[7];
    {
      const char* wfa = wsb + OFF_WFA;
#pragma unroll
      for (int i = 0; i < 7; ++i) {
        int s = w + 8 * i;
        af[i] = *(const short8*)(wfa + (((size_t)bk * 56 + s) * 64 + l) * 16);
      }
      bfr[0] = *(const short8*)(wsb + OFF_PREF + (((size_t)t * 8 + w) * 64 + l) * 16);
#pragma unroll
      for (int i = 1; i < 7; ++i) {
        int s = w + 8 * i;
        bfr[i] = *(const short8*)(wsb + OFF_XBUFA + (size_t)par * 49152 + ((size_t)(s - 8) * 64 + l) * 16);
      }
    }
    // conv staging: aw/awc window for this block's 16 tts
    const int cb = bk >> 4, tt0 = (bk & 15) << 4;
    if (th < 64) {
      int pos = tt0 - 16 + th;
      bool ok = (pos >= 0 && pos < 256);
      s1aw[th]  = ok ? awp[cb * 256 + pos] : 0.f;
      s1awc[th] = ok ? awcp[cb * 256 + pos] : 0.f;
    }
    __syncthreads();
    {  // conv: one output per thread -> convT[b][tt][f]
      int ttl = th >> 5, f = th & 31;
      float a = 0.f;
      const float* w0 = s1cw + f * 62;
#pragma unroll
      for (int kk = 0; kk < 31; ++kk) {
        a += s1aw[ttl + kk + 1] * w0[kk] + s1awc[ttl + kk + 1] * w0[31 + kk];
      }
      convT[bk * 512 + th] = a;
    }
    f32x4 acc = {0.f, 0.f, 0.f, 0.f};
#pragma unroll
    for (int i = 0; i < 7; ++i)
      acc = __builtin_amdgcn_mfma_f32_16x16x32_bf16(af[i], bfr[i], acc, 0, 0, 0);
    // reduce partial C across 8 waves
#pragma unroll
    for (int r4 = 0; r4 < 4; ++r4)
      smC[w * 256 + ((l >> 4) * 4 + r4) * 16 + (l & 15)] = acc[r4];
    __syncthreads();
    if (th < 256) {
      int r = th >> 4, b2 = th & 15;
      float s = 0.f;
#pragma unroll
      for (int w2 = 0; w2 < 8; ++w2) s += smC[w2 * 256 + r * 16 + b2];
      s += biasA[(r >> 2) * 1024 + bk * 4 + (r & 3)];
      smC[2048 + r * 16 + b2] = s;
    }
    __syncthreads();
    if (th < 64) {  // LSTM pointwise: block owns u = bk*4..+3
      int ul = th >> 4, b = th & 15, u = bk * 4 + ul;
      float gi = smC[2048 + ul * 16 + b];
      float gf = smC[2048 + (4 + ul) * 16 + b];
      float gc = smC[2048 + (8 + ul) * 16 + b];
      float go = smC[2048 + (12 + ul) * 16 + b];
      float c = actA[u * 16 + b];
      float c2 = sigmf(gf) * c + sigmf(gi) * tanhf(gc);
      float h2 = sigmf(go) * tanhf(c2);
      actA[u * 16 + b] = c2;
      ahn[b * 1024 + u] = h2;
      u16 hb = f2bf(h2);
      ((u16*)(wsb + OFF_XBUFA))[(size_t)par2 * 24576 +
          (((size_t)(16 + (u >> 5))) * 64 + ((u >> 3) & 3) * 16 + b) * 8 + (u & 7)] = hb;
      ((u16*)(wsb + OFF_AHFD))[(((size_t)(t + 1) * 32 + (u >> 5)) * 64 + ((u >> 3) & 3) * 16 + b) * 8 + (u & 7)] = hb;
    }
    grid.sync();

    // ---- S2: query (redundant per-b) + energies -> exp ----
    if (bk < 128) {
      const int b = bk >> 3, q0 = (bk & 7) << 5;
      for (int i = th; i < 1024; i += 512)
        s2conv[(i >> 5) * 33 + (i & 31)] = convT[b * 8192 + q0 * 32 + i];
      for (int i = th; i < 1024; i += 512) s2ah[i] = ahn[b * 1024 + i];
      __syncthreads();
      {  // query partials: th -> (d, quarter of K)
        int d = th & 127, part = th >> 7;
        const u16* qr = qwb + d * 1024 + part * 256;
        const float* ah = s2ah + part * 256;
        float qa = 0.f;
        for (int kk = 0; kk < 256; kk += 8) {
          short8 v = *(const short8*)(qr + kk);
#pragma unroll
          for (int e = 0; e < 8; ++e) qa += bf2f((u16)v[e]) * ah[kk + e];
        }
        smC[part * 128 + d] = qa;
      }
      __syncthreads();
      if (th < 128) s2q[th] = smC[th] + smC[128 + th] + smC[256 + th] + smC[384 + th];
      __syncthreads();
      {  // energies: 32 tt x 128 d; 16 lanes per tt, 8 d each
        int ttl = th >> 4, dl = th & 15;
        int tt = q0 + ttl;
        float e = 0.f;
        const float* pmr = pm + ((size_t)(b * 256 + tt)) * 128;
        const float* cv = s2conv + ttl * 33;
#pragma unroll
        for (int j = 0; j < 8; ++j) {
          int d = dl + (j << 4);
          float sacc = s2q[d] + pmr[d];
          const float* lw = s2ldw + d * 33;
#pragma unroll 8
          for (int f = 0; f < 32; ++f) sacc += cv[f] * lw[f];
          e += s2v[d] * tanhf(sacc);
        }
        e += __shfl_xor(e, 8); e += __shfl_xor(e, 4);
        e += __shfl_xor(e, 2); e += __shfl_xor(e, 1);
        if (dl == 0) Ebuf[b * 256 + tt] = (tt < p.mlen[b]) ? expf(e) : 0.f;
      }
    }
    grid.sync();

    // ---- S3: softmax denom + context + aw/awc/alignment ----
    {
      const int b = bk >> 4, d0 = (bk & 15) << 5;
      if (th < 256) s3e[th] = Ebuf[b * 256 + th];
      __syncthreads();
      if (th < 256) {
        float v0 = s3e[th];
#pragma unroll
        for (int off = 32; off; off >>= 1) v0 += __shfl_xor(v0, off);
        if ((th & 63) == 0) s3wr[th >> 6] = v0;
      }
      __syncthreads();
      float rden = 1.f / (s3wr[0] + s3wr[1] + s3wr[2] + s3wr[3]);
      {
        int dd = th & 31, tc = th >> 5;
        const float* mb = p.memory + ((size_t)b * 256 + tc * 16) * 512 + d0 + dd;
        float a2 = 0.f;
#pragma unroll
        for (int i = 0; i < 16; ++i) a2 += s3e[tc * 16 + i] * mb[(size_t)i * 512];
        s3part[th] = a2;
      }
      __syncthreads();
      if (th < 32) {
        float ss = 0.f;
#pragma unroll
        for (int tc = 0; tc < 16; ++tc) ss += s3part[tc * 32 + th];
        float ctx = ss * rden;
        int d = d0 + th;
        ((float*)(wsb + OFF_CTXF))[((size_t)(t + 1) * 512 + d) * 16 + b] = ctx;
        u16 cbv = f2bf(ctx);
        ((u16*)(wsb + OFF_XBUFA))[(size_t)par2 * 24576 +
            ((size_t)(d >> 5) * 64 + ((d >> 3) & 3) * 16 + b) * 8 + (d & 7)] = cbv;
        ((u16*)(wsb + OFF_CTXFD))[(((size_t)(t + 1) * 16 + (d >> 5)) * 64 + ((d >> 3) & 3) * 16 + b) * 8 + (d & 7)] = cbv;
      }
      if ((bk & 15) == 0 && th < 256) {
        float a = s3e[th] * rden;
        awp[b * 256 + th] = a;
        awcp[b * 256 + th] += a;
        p.out[82944 + ((size_t)(b * 64 + t)) * 256 + th] = a;
      }
    }
    grid.sync();
  }

  // ================= loop 2: decoder-LSTM recurrence (1 sync/step) =================
  for (int t = 0; t < 64; ++t) {
    const int par = t & 1, par2 = par ^ 1;
    short8 af2[10], bf2v[10];
    {
      const char* wfd = wsb + OFF_WFD;
#pragma unroll
      for (int i = 0; i < 10; ++i) {
        int s = w + 8 * i;
        af2[i] = *(const short8*)(wfd + (((size_t)bk * 80 + s) * 64 + l) * 16);
      }
#pragma unroll
      for (int i = 0; i < 4; ++i) {  // ah tiles 0..31
        int s = w + 8 * i;
        bf2v[i] = *(const short8*)(wsb + OFF_AHFD + (((size_t)(t + 1) * 32 + s) * 64 + l) * 16);
      }
#pragma unroll
      for (int i = 4; i < 6; ++i) {  // ctx tiles 0..15
        int s = w + 8 * i - 32;
        bf2v[i] = *(const short8*)(wsb + OFF_CTXFD + (((size_t)(t + 1) * 16 + s) * 64 + l) * 16);
      }
#pragma unroll
      for (int i = 6; i < 10; ++i) {  // dh tiles 0..31 (parity buffer)
        int s = w + 8 * i - 48;
        bf2v[i] = *(const short8*)(wsb + OFF_DHB + (size_t)par * 32768 + ((size_t)s * 64 + l) * 16);
      }
    }
    f32x4 acc = {0.f, 0.f, 0.f, 0.f};
#pragma unroll
    for (int i = 0; i < 10; ++i)
      acc = __builtin_amdgcn_mfma_f32_16x16x32_bf16(af2[i], bf2v[i], acc, 0, 0, 0);
#pragma unroll
    for (int r4 = 0; r4 < 4; ++r4)
      smC[w * 256 + ((l >> 4) * 4 + r4) * 16 + (l & 15)] = acc[r4];
    __syncthreads();
    if (th < 256) {
      int r = th >> 4, b2 = th & 15;
      float s = 0.f;
#pragma unroll
      for (int w2 = 0; w2 < 8; ++w2) s += smC[w2 * 256 + r * 16 + b2];
      s += biasD[(r >> 2) * 1024 + bk * 4 + (r & 3)];
      smC[2048 + r * 16 + b2] = s;
    }
    __syncthreads();
    if (th < 64) {
      int ul = th >> 4, b = th & 15, u = bk * 4 + ul;
      float gi = smC[2048 + ul * 16 + b];
      float gf = smC[2048 + (4 + ul) * 16 + b];
      float gc = smC[2048 + (8 + ul) * 16 + b];
      float go = smC[2048 + (12 + ul) * 16 + b];
      float c = actD[u * 16 + b];
      float c2 = sigmf(gf) * c + sigmf(gi) * tanhf(gc);
      float h2 = sigmf(go) * tanhf(c2);
      actD[u * 16 + b] = c2;
      ((float*)(wsb + OFF_DHF))[((size_t)(t + 1) * 1024 + u) * 16 + b] = h2;
      ((u16*)(wsb + OFF_DHB))[(size_t)par2 * 16384 +
          ((size_t)(u >> 5) * 64 + ((u >> 3) & 3) * 16 + b) * 8 + (u & 7)] = f2bf(h2);
    }
    grid.sync();
  }

  // ================= epilogue: mel + gate projections =================
  {
    int t = bk & 63, pa = bk >> 6;
    const float* dh = (const float*)(wsb + OFF_DHF) + (size_t)(t + 1) * 16384;
    const float* cx = (const float*)(wsb + OFF_CTXF) + (size_t)(t + 1) * 8192;
    int lim = (pa == 3) ? 336 : 320;
    for (int idx = th; idx < lim; idx += 512) {
      if (idx < 320) {
        int mi = idx >> 4, b = idx & 15, m = pa * 20 + mi;
        const float* wr = p.projW + (size_t)m * 1536;
        float a0 = 0.f, a1 = 0.f;
#pragma unroll 4
        for (int k = 0; k < 1024; k += 2) { a0 += wr[k] * dh[k * 16 + b]; a1 += wr[k + 1] * dh[(k + 1) * 16 + b]; }
#pragma unroll 4
        for (int k = 0; k < 512; k += 2)  { a0 += wr[1024 + k] * cx[k * 16 + b]; a1 += wr[1025 + k] * cx[(k + 1) * 16 + b]; }
        p.out[((size_t)(b * 80 + m)) * 64 + t] = a0 + a1 + p.projb[m];
      } else {
        int b = idx - 320;
        float a0 = 0.f, a1 = 0.f;
#pragma unroll 4
        for (int k = 0; k < 1024; k += 2) { a0 += p.gateW[k] * dh[k * 16 + b]; a1 += p.gateW[k + 1] * dh[(k + 1) * 16 + b]; }
#pragma unroll 4
        for (int k = 0; k < 512; k += 2)  { a0 += p.gateW[1024 + k] * cx[k * 16 + b]; a1 += p.gateW[1025 + k] * cx[(k + 1) * 16 + b]; }
        p.out[81920 + b * 64 + t] = a0 + a1 + p.gateb[0];
      }
    }
  }
}

// ---------------- host launcher ----------------
extern "C" void kernel_launch(void* const* d_in, const int* in_sizes, int n_in,
                              void* d_out, int out_size, void* d_ws, size_t ws_size,
                              hipStream_t stream) {
  (void)in_sizes; (void)n_in; (void)out_size; (void)ws_size;
  const float* memory = (const float*)d_in[0];
  const float* dec_in = (const float*)d_in[1];
  const int*   mlen   = (const int*)d_in[2];
  const float* pW1    = (const float*)d_in[3];
  const float* pb1    = (const float*)d_in[4];
  const float* pW2    = (const float*)d_in[5];
  const float* pb2    = (const float*)d_in[6];
  const float* aWih   = (const float*)d_in[7];
  const float* aWhh   = (const float*)d_in[8];
  const float* abih   = (const float*)d_in[9];
  const float* abhh   = (const float*)d_in[10];
  const float* qW     = (const float*)d_in[11];
  const float* memW   = (const float*)d_in[12];
  const float* convW  = (const float*)d_in[13];
  const float* ldW    = (const float*)d_in[14];
  const float* attnv  = (const float*)d_in[15];
  const float* dWih   = (const float*)d_in[16];
  const float* dWhh   = (const float*)d_in[17];
  const float* dbih   = (const float*)d_in[18];
  const float* dbhh   = (const float*)d_in[19];
  const float* projW  = (const float*)d_in[20];
  const float* projb  = (const float*)d_in[21];
  const float* gateW  = (const float*)d_in[22];
  const float* gateb  = (const float*)d_in[23];
  char* wsb = (char*)d_ws;
  float* out = (float*)d_out;

  hipMemsetAsync(wsb + OFF_XBUFA, 0, ZERO_BYTES, stream);

  hipLaunchKernelGGL(k_wfrag, dim3(3584), dim3(256), 0, stream, aWih, aWhh, wsb + OFF_WFA, 56, 768);
  hipLaunchKernelGGL(k_wfrag, dim3(5120), dim3(256), 0, stream, dWih, dWhh, wsb + OFF_WFD, 80, 1536);
  hipLaunchKernelGGL(k_smallprep, dim3(800), dim3(256), 0, stream, memW, abih, abhh, dbih, dbhh, qW, wsb);
  hipLaunchKernelGGL(k_prenet, dim3(64, 16), dim3(256), 0, stream, dec_in, pW1, pb1, pW2, pb2, wsb);
  hipLaunchKernelGGL(k_pm, dim3(256), dim3(256), 0, stream, memory, wsb);

  KParams p{memory, mlen, convW, ldW, attnv, projW, projb, gateW, gateb, wsb, out};
  void* args[] = { &p };
  hipLaunchCooperativeKernel((void*)k_main, dim3(256), dim3(512), args, 0, stream);
}

// Round 3
// 6313.535 us; speedup vs baseline: 2.1705x; 1.4363x over previous
//
#include <hip/hip_runtime.h>

typedef __attribute__((ext_vector_type(8))) short short8;
typedef __attribute__((ext_vector_type(4))) float f32x4;
typedef unsigned short u16;
typedef unsigned int u32;
typedef unsigned long long u64;

// Shapes: B=16, T_ENC=256, T_DEC=64, N_MEL=80, ENC=512, ARNN=DRNN=1024,
// PRENET=256, ATTN_DIM=128, LOC_F=32, LOC_K=31
// attn LSTM K = 1792 (56 tiles of 32); dec K = 2560 (80 tiles)
// MFMA 16x16x32 bf16; C/D: col=lane&15, row=(lane>>4)*4+reg  [HW-verified]

// ---------------- workspace byte offsets ----------------
static constexpr size_t OFF_WFA   = 0;                 // 14,680,064
static constexpr size_t OFF_WFD   = 14680064;          // 20,971,520
static constexpr size_t OFF_PREF  = 35651584;          // 524,288
static constexpr size_t OFF_QWB   = 36175872;          // 262,144
static constexpr size_t OFF_MWT   = 36438016;          // 262,144
static constexpr size_t OFF_BA    = 36700160;          // 16,384
static constexpr size_t OFF_BD    = 36716544;          // 16,384
static constexpr size_t OFF_PM    = 36732928;          // 2,097,152
static constexpr size_t OFF_CTXF  = 38830080;          // 65*512*16*4 = 2,129,920
static constexpr size_t OFF_DHF   = 40960000;          // 65*1024*16*4 = 4,259,840
static constexpr size_t OFF_AHFD  = 45219840;          // 65*32*1024 = 2,129,920
static constexpr size_t OFF_CTXFD = 47349760;          // 65*16*1024 = 1,064,960
// ---- zero-init region ----
static constexpr size_t OFF_XBUFA = 48414720;          // 2*48*1024 = 98,304
static constexpr size_t OFF_DHB   = 48513024;          // 2*32*1024 = 65,536
static constexpr size_t OFF_AHN   = 48578560;          // 16*1024*4 = 65,536
static constexpr size_t OFF_BAR   = 48644096;          // 4,096 (16 counters @64B stride)
static constexpr size_t OFF_END   = 48648192;
static constexpr size_t ZERO_BYTES = OFF_END - OFF_XBUFA;  // 233,472

__device__ __forceinline__ float sigmf(float x) { return 1.f / (1.f + expf(-x)); }
__device__ __forceinline__ float tanh_fast(float x) {
  float e2 = __expf(2.f * x);
  return 1.f - 2.f / (e2 + 1.f);
}
__device__ __forceinline__ u16 f2bf(float f) {
  u32 u = __float_as_uint(f);
  return (u16)((u + 0x7FFFu + ((u >> 16) & 1u)) >> 16);
}
__device__ __forceinline__ float bf2f(u16 x) { return __uint_as_float(((u32)x) << 16); }

// agent-scope (LLC, bypass non-coherent L1/L2) helpers
__device__ __forceinline__ short8 ld_frag_agent(const void* ptr) {
  const u64* q = (const u64*)ptr;
  u64 lo = __hip_atomic_load(q, __ATOMIC_RELAXED, __HIP_MEMORY_SCOPE_AGENT);
  u64 hi = __hip_atomic_load(q + 1, __ATOMIC_RELAXED, __HIP_MEMORY_SCOPE_AGENT);
  union { u64 q2[2]; short8 s; } u;
  u.q2[0] = lo; u.q2[1] = hi;
  return u.s;
}
__device__ __forceinline__ void st_u16_agent(u16* p, u16 v) {
  __hip_atomic_store(p, v, __ATOMIC_RELAXED, __HIP_MEMORY_SCOPE_AGENT);
}
__device__ __forceinline__ void st_f32_agent(float* p, float v) {
  __hip_atomic_store(p, v, __ATOMIC_RELAXED, __HIP_MEMORY_SCOPE_AGENT);
}

// distributed cumulative-counter grid barrier (no L2 flush/invalidate).
// Sound because a block can only arrive at epoch N+1 after observing sum>=256*N,
// which requires every block to have arrived at N (max spread 1 epoch).
__device__ __forceinline__ void gbar(u32* bar, int bk, int th, u32 epoch) {
  __syncthreads();   // drains vmcnt -> all agent stores visible at LLC
  if (th == 0) {
    __hip_atomic_fetch_add(bar + (bk & 15) * 16, 1u, __ATOMIC_RELAXED, __HIP_MEMORY_SCOPE_AGENT);
    u32 target = epoch * 256u;
    for (;;) {
      u32 sum = 0;
#pragma unroll
      for (int i = 0; i < 16; ++i)
        sum += __hip_atomic_load(bar + i * 16, __ATOMIC_RELAXED, __HIP_MEMORY_SCOPE_AGENT);
      if (sum >= target) break;
      __builtin_amdgcn_s_sleep(1);
    }
  }
  __syncthreads();
}

// ---------------- prep: LSTM weights -> bf16 A-fragment layout ----------------
__global__ void k_wfrag(const float* __restrict__ Wih, const float* __restrict__ Whh,
                        char* __restrict__ dst, int NT, int Kih) {
  int idx = blockIdx.x * 256 + threadIdx.x;   // (bk*NT + s)*64 + l
  int l = idx & 63;
  int st = idx >> 6;
  int s = st % NT, bk = st / NT;
  int r = l & 15, kg = l >> 4;
  int j = (r >> 2) * 1024 + bk * 4 + (r & 3);
  int k0 = s * 32 + kg * 8;
  const float* src = (k0 < Kih) ? (Wih + (size_t)j * Kih + k0)
                                : (Whh + (size_t)j * 1024 + (k0 - Kih));
  short8 v;
#pragma unroll
  for (int e = 0; e < 8; ++e) v[e] = (short)f2bf(src[e]);
  *(short8*)(dst + (size_t)idx * 16) = v;
}

// ---------------- prep: memW^T, combined biases, qW bf16 ----------------
__global__ void k_smallprep(const float* __restrict__ memW,
                            const float* __restrict__ abih, const float* __restrict__ abhh,
                            const float* __restrict__ dbih, const float* __restrict__ dbhh,
                            const float* __restrict__ qW, char* __restrict__ wsb) {
  int idx = blockIdx.x * 256 + threadIdx.x;
  if (idx < 65536) {
    int k = idx >> 7, d = idx & 127;
    ((float*)(wsb + OFF_MWT))[idx] = memW[d * 512 + k];
  } else if (idx < 69632) {
    int j = idx - 65536;
    ((float*)(wsb + OFF_BA))[j] = abih[j] + abhh[j];
  } else if (idx < 73728) {
    int j = idx - 69632;
    ((float*)(wsb + OFF_BD))[j] = dbih[j] + dbhh[j];
  } else if (idx < 204800) {
    int j = idx - 73728;
    ((u16*)(wsb + OFF_QWB))[j] = f2bf(qW[j]);
  }
}

// ---------------- prep: prenet -> bf16 B-fragment layout per step ----------------
__global__ void k_prenet(const float* __restrict__ dec_in,
                         const float* __restrict__ W1, const float* __restrict__ b1,
                         const float* __restrict__ W2, const float* __restrict__ b2,
                         char* __restrict__ wsb) {
  int s = blockIdx.x, b = blockIdx.y, th = threadIdx.x;
  __shared__ float frame[80];
  __shared__ float h1[256];
  if (th < 80) frame[th] = (s == 0) ? 0.f : dec_in[(b * 80 + th) * 64 + (s - 1)];
  __syncthreads();
  float a = b1[th];
  const float* w1r = W1 + th * 80;
  for (int m = 0; m < 80; ++m) a += w1r[m] * frame[m];
  h1[th] = fmaxf(a, 0.f);
  __syncthreads();
  float a2 = b2[th];
  const float* w2r = W2 + th * 256;
  for (int i = 0; i < 256; ++i) a2 += w2r[i] * h1[i];
  float pre = fmaxf(a2, 0.f);
  int k = th;
  ((u16*)(wsb + OFF_PREF))[(((size_t)s * 8 + (k >> 5)) * 64 + ((k >> 3) & 3) * 16 + b) * 8 + (k & 7)] = f2bf(pre);
}

// ---------------- prep: processed_memory ----------------
__global__ void k_pm(const float* __restrict__ memory, char* __restrict__ wsb) {
  int bk = blockIdx.x, th = threadIdx.x;
  int b = bk >> 4, t0 = (bk & 15) * 16;
  __shared__ float mrow[16 * 512];
  for (int i = 0; i < 8; ++i) {
    int fi4 = i * 256 + th;
    int tl = fi4 >> 7, k4 = (fi4 & 127) << 2;
    *(float4*)&mrow[tl * 512 + k4] =
        *(const float4*)&memory[((size_t)(b * 256 + t0 + tl)) * 512 + k4];
  }
  __syncthreads();
  int d = th & 127, tl0 = th >> 7;
  float acc[8] = {};
  const float* mWT = (const float*)(wsb + OFF_MWT);
  float* pmw = (float*)(wsb + OFF_PM);
  for (int k = 0; k < 512; ++k) {
    float w = mWT[k * 128 + d];
#pragma unroll
    for (int i = 0; i < 8; ++i) acc[i] += w * mrow[(tl0 + i * 2) * 512 + k];
  }
  for (int i = 0; i < 8; ++i)
    pmw[((size_t)(b * 256 + t0 + tl0 + i * 2)) * 128 + d] = acc[i];
}

struct KParams {
  const float* memory;
  const int* mlen;
  const float* convW;
  const float* ldW;
  const float* attnv;
  const float* projW;
  const float* projb;
  const float* gateW;
  const float* gateb;
  char* wsb;
  float* out;
};

// ---------------- main persistent kernel (custom barriers, no grid.sync) -------
__global__ void __launch_bounds__(512, 2) k_main(KParams p) {
  const int th = threadIdx.x;
  const int bk = blockIdx.x;
  char* wsb = p.wsb;
  const int l = th & 63, w = th >> 6;
  u32* bar = (u32*)(wsb + OFF_BAR);
  u32 ep = 0;

  __shared__ float smC[2304];
  __shared__ float s2q[128], s2v[128];
  __shared__ float s2ldw[4224];               // [128][33] f32
  __shared__ float s_conv[1056];              // [32][33] per-chunk conv
  __shared__ __align__(16) float s2ah[1024];
  __shared__ float s_e[256], s3wr[4];
  __shared__ float s1cw[1984];                // convW 32*62
  __shared__ float s_aw[256], s_awc[256];     // persistent attention state (per-b block)

  const float* pm = (const float*)(wsb + OFF_PM);
  const u16* qwb = (const u16*)(wsb + OFF_QWB);

  // persistent LDS staging (step-invariant)
  for (int i = th; i < 1984; i += 512) s1cw[i] = p.convW[i];
  for (int i = th; i < 4096; i += 512) s2ldw[(i >> 5) * 33 + (i & 31)] = p.ldW[i];
  if (th < 128) s2v[th] = p.attnv[th];
  if (th < 256) { s_aw[th] = 0.f; s_awc[th] = 0.f; }

  // step-invariant registers
  float bA = 0.f, bD = 0.f;
  if (th < 256) {
    int r = th >> 4;
    bA = ((const float*)(wsb + OFF_BA))[(r >> 2) * 1024 + bk * 4 + (r & 3)];
    bD = ((const float*)(wsb + OFF_BD))[(r >> 2) * 1024 + bk * 4 + (r & 3)];
  }
  int len = 0;
  if (bk < 16) len = p.mlen[bk];
  float cA = 0.f, cD = 0.f;   // register-resident LSTM cell states (th<64)

  // preload step-invariant attn A-fragments (7 tiles/wave, 28 VGPRs)
  short8 afA[7];
  {
    const char* wfa = wsb + OFF_WFA;
#pragma unroll
    for (int i = 0; i < 7; ++i)
      afA[i] = *(const short8*)(wfa + (((size_t)bk * 56 + (w + 8 * i)) * 64 + l) * 16);
  }
  __syncthreads();

  // ================= loop 1: attention recurrence (2 barriers/step) ============
  for (int t = 0; t < 64; ++t) {
    const int par = t & 1, par2 = par ^ 1;

    // ---- Phase A: attn-LSTM gates (MFMA) + pointwise ----
    {
      short8 bfr[7];
      bfr[0] = *(const short8*)(wsb + OFF_PREF + (((size_t)t * 8 + w) * 64 + l) * 16);
#pragma unroll
      for (int i = 1; i < 7; ++i)
        bfr[i] = ld_frag_agent(wsb + OFF_XBUFA + (size_t)par * 49152 +
                               ((size_t)(w + 8 * i - 8) * 64 + l) * 16);
      f32x4 acc = {0.f, 0.f, 0.f, 0.f};
#pragma unroll
      for (int i = 0; i < 7; ++i)
        acc = __builtin_amdgcn_mfma_f32_16x16x32_bf16(afA[i], bfr[i], acc, 0, 0, 0);
#pragma unroll
      for (int r4 = 0; r4 < 4; ++r4)
        smC[w * 256 + ((l >> 4) * 4 + r4) * 16 + (l & 15)] = acc[r4];
      __syncthreads();
      if (th < 256) {
        int r = th >> 4, b2 = th & 15;
        float s = 0.f;
#pragma unroll
        for (int w2 = 0; w2 < 8; ++w2) s += smC[w2 * 256 + r * 16 + b2];
        smC[2048 + r * 16 + b2] = s + bA;
      }
      __syncthreads();
      if (th < 64) {
        int ul = th >> 4, b = th & 15, u = bk * 4 + ul;
        float gi = smC[2048 + ul * 16 + b];
        float gf = smC[2048 + (4 + ul) * 16 + b];
        float gc = smC[2048 + (8 + ul) * 16 + b];
        float go = smC[2048 + (12 + ul) * 16 + b];
        float c2 = sigmf(gf) * cA + sigmf(gi) * tanhf(gc);
        float h2 = sigmf(go) * tanhf(c2);
        cA = c2;
        st_f32_agent((float*)(wsb + OFF_AHN) + b * 1024 + u, h2);
        u16 hb = f2bf(h2);
        st_u16_agent((u16*)(wsb + OFF_XBUFA) + (size_t)par2 * 24576 +
                     (((size_t)(16 + (u >> 5)) * 64 + ((u >> 3) & 3) * 16 + b) * 8 + (u & 7)), hb);
        st_u16_agent((u16*)(wsb + OFF_AHFD) +
                     ((((size_t)(t + 1) * 32 + (u >> 5)) * 64 + ((u >> 3) & 3) * 16 + b) * 8 + (u & 7)), hb);
      }
    }
    gbar(bar, bk, th, ++ep);

    // ---- Phase B: full attention for one b per block (16 active blocks) ----
    if (bk < 16) {
      const int b = bk;
      // stage ah (agent loads) into LDS
      {
        const u64* src = (const u64*)((float*)(wsb + OFF_AHN) + (size_t)b * 1024);
        ((u64*)s2ah)[th] = __hip_atomic_load(src + th, __ATOMIC_RELAXED, __HIP_MEMORY_SCOPE_AGENT);
      }
      __syncthreads();
      // query partials: d = th&127, quarter = th>>7
      {
        int d = th & 127, part = th >> 7;
        const u16* qr = qwb + d * 1024 + part * 256;
        const float* ah = s2ah + part * 256;
        float qa = 0.f;
        for (int kk = 0; kk < 256; kk += 8) {
          short8 v = *(const short8*)(qr + kk);
#pragma unroll
          for (int e = 0; e < 8; ++e) qa += bf2f((u16)v[e]) * ah[kk + e];
        }
        smC[part * 128 + d] = qa;
      }
      __syncthreads();
      if (th < 128) s2q[th] = smC[th] + smC[128 + th] + smC[256 + th] + smC[384 + th];
      // conv + energies in 8 chunks of 32 tt (s2q visible after first chunk sync)
      for (int c = 0; c < 8; ++c) {
        int tt0 = c * 32;
        {
          int f = th & 31, ttl = th >> 5;
#pragma unroll
          for (int j = 0; j < 2; ++j) {
            int ttL = ttl + j * 16;
            int tt = tt0 + ttL;
            float a = 0.f;
            const float* w0 = s1cw + f * 62;
#pragma unroll
            for (int kk = 0; kk < 31; ++kk) {
              int pos = tt + kk - 15;
              bool ok = (pos >= 0 && pos < 256);
              float awv = ok ? s_aw[pos] : 0.f;
              float awcv = ok ? s_awc[pos] : 0.f;
              a += awv * w0[kk] + awcv * w0[31 + kk];
            }
            s_conv[ttL * 33 + f] = a;
          }
        }
        __syncthreads();
        {
          int ttL = th >> 4, dl = th & 15;
          int tt = tt0 + ttL;
          float e = 0.f;
          const float* pmr = pm + ((size_t)(b * 256 + tt)) * 128;
          const float* cv = s_conv + ttL * 33;
#pragma unroll
          for (int j = 0; j < 8; ++j) {
            int d2 = dl + (j << 4);
            float sacc = s2q[d2] + pmr[d2];
            const float* lw = s2ldw + d2 * 33;
#pragma unroll 8
            for (int f = 0; f < 32; ++f) sacc += cv[f] * lw[f];
            e += s2v[d2] * tanh_fast(sacc);
          }
          e += __shfl_xor(e, 8); e += __shfl_xor(e, 4);
          e += __shfl_xor(e, 2); e += __shfl_xor(e, 1);
          if (dl == 0) s_e[tt] = (tt < len) ? __expf(e) : 0.f;
        }
        __syncthreads();
      }
      // softmax denom
      if (th < 256) {
        float v0 = s_e[th];
#pragma unroll
        for (int off = 32; off; off >>= 1) v0 += __shfl_xor(v0, off);
        if ((th & 63) == 0) s3wr[th >> 6] = v0;
      }
      __syncthreads();
      float rden = 1.f / (s3wr[0] + s3wr[1] + s3wr[2] + s3wr[3]);
      if (th < 256) {
        float a = s_e[th] * rden;
        s_aw[th] = a;
        s_awc[th] += a;
        p.out[82944 + ((size_t)(b * 64 + t)) * 256 + th] = a;
      }
      __syncthreads();
      // context: one d per thread (512 d)
      {
        const int d = th;
        const float* mb = p.memory + ((size_t)b * 256) * 512 + d;
        float a0 = 0.f, a1 = 0.f, a2 = 0.f, a3 = 0.f;
#pragma unroll 4
        for (int tt = 0; tt < 256; tt += 4) {
          a0 += s_aw[tt] * mb[(size_t)tt * 512];
          a1 += s_aw[tt + 1] * mb[(size_t)(tt + 1) * 512];
          a2 += s_aw[tt + 2] * mb[(size_t)(tt + 2) * 512];
          a3 += s_aw[tt + 3] * mb[(size_t)(tt + 3) * 512];
        }
        float ctxv = (a0 + a1) + (a2 + a3);
        st_f32_agent((float*)(wsb + OFF_CTXF) + ((size_t)(t + 1) * 512 + d) * 16 + b, ctxv);
        u16 cb2 = f2bf(ctxv);
        st_u16_agent((u16*)(wsb + OFF_XBUFA) + (size_t)par2 * 24576 +
                     (((size_t)(d >> 5) * 64 + ((d >> 3) & 3) * 16 + b) * 8 + (d & 7)), cb2);
        st_u16_agent((u16*)(wsb + OFF_CTXFD) +
                     ((((size_t)(t + 1) * 16 + (d >> 5)) * 64 + ((d >> 3) & 3) * 16 + b) * 8 + (d & 7)), cb2);
      }
    }
    gbar(bar, bk, th, ++ep);
  }

  // ================= loop 2: decoder-LSTM recurrence (1 barrier/step) ==========
  short8 afD[10];
  {
    const char* wfd = wsb + OFF_WFD;
#pragma unroll
    for (int i = 0; i < 10; ++i)
      afD[i] = *(const short8*)(wfd + (((size_t)bk * 80 + (w + 8 * i)) * 64 + l) * 16);
  }
  for (int t = 0; t < 64; ++t) {
    const int par = t & 1, par2 = par ^ 1;
    short8 xv[10];
#pragma unroll
    for (int i = 0; i < 4; ++i)
      xv[i] = ld_frag_agent(wsb + OFF_AHFD + (((size_t)(t + 1) * 32 + (w + 8 * i)) * 64 + l) * 16);
#pragma unroll
    for (int i = 4; i < 6; ++i)
      xv[i] = ld_frag_agent(wsb + OFF_CTXFD + (((size_t)(t + 1) * 16 + (w + 8 * i - 32)) * 64 + l) * 16);
#pragma unroll
    for (int i = 6; i < 10; ++i)
      xv[i] = ld_frag_agent(wsb + OFF_DHB + (size_t)par * 32768 +
                            ((size_t)(w + 8 * i - 48) * 64 + l) * 16);
    f32x4 acc = {0.f, 0.f, 0.f, 0.f};
#pragma unroll
    for (int i = 0; i < 10; ++i)
      acc = __builtin_amdgcn_mfma_f32_16x16x32_bf16(afD[i], xv[i], acc, 0, 0, 0);
#pragma unroll
    for (int r4 = 0; r4 < 4; ++r4)
      smC[w * 256 + ((l >> 4) * 4 + r4) * 16 + (l & 15)] = acc[r4];
    __syncthreads();
    if (th < 256) {
      int r = th >> 4, b2 = th & 15;
      float s = 0.f;
#pragma unroll
      for (int w2 = 0; w2 < 8; ++w2) s += smC[w2 * 256 + r * 16 + b2];
      smC[2048 + r * 16 + b2] = s + bD;
    }
    __syncthreads();
    if (th < 64) {
      int ul = th >> 4, b = th & 15, u = bk * 4 + ul;
      float gi = smC[2048 + ul * 16 + b];
      float gf = smC[2048 + (4 + ul) * 16 + b];
      float gc = smC[2048 + (8 + ul) * 16 + b];
      float go = smC[2048 + (12 + ul) * 16 + b];
      float c2 = sigmf(gf) * cD + sigmf(gi) * tanhf(gc);
      float h2 = sigmf(go) * tanhf(c2);
      cD = c2;
      st_f32_agent((float*)(wsb + OFF_DHF) + ((size_t)(t + 1) * 1024 + u) * 16 + b, h2);
      st_u16_agent((u16*)(wsb + OFF_DHB) + (size_t)par2 * 16384 +
                   (((size_t)(u >> 5) * 64 + ((u >> 3) & 3) * 16 + b) * 8 + (u & 7)), f2bf(h2));
    }
    gbar(bar, bk, th, ++ep);
  }

  // ================= epilogue: mel + gate projections =================
  // Plain loads are safe: DHF/CTXF each written exactly once (agent stores ->
  // LLC) before the final barrier, and never plain-read earlier this launch;
  // replay-cached values are bitwise identical (deterministic kernel).
  {
    int t = bk & 63, pa = bk >> 6;
    const float* dh = (const float*)(wsb + OFF_DHF) + (size_t)(t + 1) * 16384;
    const float* cx = (const float*)(wsb + OFF_CTXF) + (size_t)(t + 1) * 8192;
    int lim = (pa == 3) ? 336 : 320;
    for (int idx = th; idx < lim; idx += 512) {
      if (idx < 320) {
        int mi = idx >> 4, b = idx & 15, m = pa * 20 + mi;
        const float* wr = p.projW + (size_t)m * 1536;
        float a0 = 0.f, a1 = 0.f;
#pragma unroll 8
        for (int k = 0; k < 1024; k += 2) { a0 += wr[k] * dh[k * 16 + b]; a1 += wr[k + 1] * dh[(k + 1) * 16 + b]; }
#pragma unroll 8
        for (int k = 0; k < 512; k += 2)  { a0 += wr[1024 + k] * cx[k * 16 + b]; a1 += wr[1025 + k] * cx[(k + 1) * 16 + b]; }
        p.out[((size_t)(b * 80 + m)) * 64 + t] = a0 + a1 + p.projb[m];
      } else {
        int b = idx - 320;
        float a0 = 0.f, a1 = 0.f;
#pragma unroll 8
        for (int k = 0; k < 1024; k += 2) { a0 += p.gateW[k] * dh[k * 16 + b]; a1 += p.gateW[k + 1] * dh[(k + 1) * 16 + b]; }
#pragma unroll 8
        for (int k = 0; k < 512; k += 2)  { a0 += p.gateW[1024 + k] * cx[k * 16 + b]; a1 += p.gateW[1025 + k] * cx[(k + 1) * 16 + b]; }
        p.out[81920 + b * 64 + t] = a0 + a1 + p.gateb[0];
      }
    }
  }
}

// ---------------- host launcher ----------------
extern "C" void kernel_launch(void* const* d_in, const int* in_sizes, int n_in,
                              void* d_out, int out_size, void* d_ws, size_t ws_size,
                              hipStream_t stream) {
  (void)in_sizes; (void)n_in; (void)out_size; (void)ws_size;
  const float* memory = (const float*)d_in[0];
  const float* dec_in = (const float*)d_in[1];
  const int*   mlen   = (const int*)d_in[2];
  const float* pW1    = (const float*)d_in[3];
  const float* pb1    = (const float*)d_in[4];
  const float* pW2    = (const float*)d_in[5];
  const float* pb2    = (const float*)d_in[6];
  const float* aWih   = (const float*)d_in[7];
  const float* aWhh   = (const float*)d_in[8];
  const float* abih   = (const float*)d_in[9];
  const float* abhh   = (const float*)d_in[10];
  const float* qW     = (const float*)d_in[11];
  const float* memW   = (const float*)d_in[12];
  const float* convW  = (const float*)d_in[13];
  const float* ldW    = (const float*)d_in[14];
  const float* attnv  = (const float*)d_in[15];
  const float* dWih   = (const float*)d_in[16];
  const float* dWhh   = (const float*)d_in[17];
  const float* dbih   = (const float*)d_in[18];
  const float* dbhh   = (const float*)d_in[19];
  const float* projW  = (const float*)d_in[20];
  const float* projb  = (const float*)d_in[21];
  const float* gateW  = (const float*)d_in[22];
  const float* gateb  = (const float*)d_in[23];
  char* wsb = (char*)d_ws;
  float* out = (float*)d_out;

  hipMemsetAsync(wsb + OFF_XBUFA, 0, ZERO_BYTES, stream);

  hipLaunchKernelGGL(k_wfrag, dim3(3584), dim3(256), 0, stream, aWih, aWhh, wsb + OFF_WFA, 56, 768);
  hipLaunchKernelGGL(k_wfrag, dim3(5120), dim3(256), 0, stream, dWih, dWhh, wsb + OFF_WFD, 80, 1536);
  hipLaunchKernelGGL(k_smallprep, dim3(800), dim3(256), 0, stream, memW, abih, abhh, dbih, dbhh, qW, wsb);
  hipLaunchKernelGGL(k_prenet, dim3(64, 16), dim3(256), 0, stream, dec_in, pW1, pb1, pW2, pb2, wsb);
  hipLaunchKernelGGL(k_pm, dim3(256), dim3(256), 0, stream, memory, wsb);

  KParams p{memory, mlen, convW, ldW, attnv, projW, projb, gateW, gateb, wsb, out};
  void* args[] = { &p };
  hipLaunchCooperativeKernel((void*)k_main, dim3(256), dim3(512), args, 0, stream);
}